// Round 10
// baseline (237.786 us; speedup 1.0000x reference)
//
#include <hip/hip_runtime.h>

#define BATCH 256
#define TT 1024
#define NN 64
#define CHUNK 64
#define NCH 16
#define SOS 1
#define EOSI 2
#define LN2F 0.6931471805599453f
#define LOG2E 1.4426950408889634f

typedef short bf16x8 __attribute__((ext_vector_type(8)));
typedef float f32x4 __attribute__((ext_vector_type(4)));

__device__ __forceinline__ unsigned short f2bf(float x) {
  unsigned u = __float_as_uint(x);
  u += 0x7fffu + ((u >> 16) & 1u);
  return (unsigned short)(u >> 16);
}
__device__ __forceinline__ float bf2f(unsigned short v) { return __uint_as_float(((unsigned)v) << 16); }
__device__ __forceinline__ unsigned cvtpk(float lo, float hi) {
  unsigned r;
  asm("v_cvt_pk_bf16_f32 %0, %1, %2" : "=v"(r) : "v"(lo), "v"(hi));
  return r;
}

// Panel-local tiled address (validated R5-R9)
__device__ __forceinline__ int padr(int k, int c) {
  return ((k >> 5) << 10) + (((k >> 3) & 3) << 8) + (c << 4) + ((k & 7) << 1);
}

__device__ __forceinline__ int wave_len(const float* mask, int b, int l) {
  float ls = 0.f;
#pragma unroll
  for (int c = 0; c < 4; ++c) {
    float4 m4 = *reinterpret_cast<const float4*>(mask + (size_t)b * TT + c * 256 + l * 4);
    ls += (m4.x + m4.y) + (m4.z + m4.w);
  }
#pragma unroll
  for (int m = 1; m < 64; m <<= 1) ls += __shfl_xor(ls, m, 64);
  return (int)(ls + 0.5f);
}

// ---- Kernel A: block = (batch b, pair cp); each of 4 waves evolves panel w of chunk cp then 15-cp ----
__global__ __launch_bounds__(256, 6) void crf_chunk(const float* __restrict__ h,
                                                    const float* __restrict__ mask,
                                                    const float* __restrict__ trans,
                                                    unsigned short* __restrict__ mats,
                                                    int* __restrict__ scalesI) {
  __shared__ __align__(16) char lds[4 * 2048 + 4 * 256];  // 4 panels + 4 bf16 eh ping-pong
  const int tid = threadIdx.x;
  const int w = tid >> 6, l = tid & 63;
  const int h4 = l >> 4, cl = l & 15;
  const int b = blockIdx.x >> 3;       // 256 batches
  const int cp = blockIdx.x & 7;       // pair {cp, 15-cp}: E[steps] == 64 for every pair

  char* P = lds + w * 2048;
  char* ehB = lds + 8192 + w * 256;
  const int wp = 2 * (16 * ((l >> 2) & 3) + 4 * (l >> 4) + (l & 3));

  const int len = wave_len(mask, b, l);

  // E fragments (A operand) — computed ONCE, reused for both chunks (validated R3-R9)
  bf16x8 ef[4][2];
#pragma unroll
  for (int I = 0; I < 4; ++I)
#pragma unroll
    for (int Kc = 0; Kc < 2; ++Kc) {
      const float* p = trans + (16 * I + cl) * 64 + 32 * Kc + 8 * h4;
      bf16x8 v;
#pragma unroll
      for (int e = 0; e < 8; ++e) v[e] = (short)f2bf(__expf(p[e]));
      ef[I][Kc] = v;
    }

  for (int half = 0; half < 2; ++half) {
    const int c = half ? (NCH - 1 - cp) : cp;
    const int t0 = c * CHUNK;
    if (t0 >= len) continue;
    const int nstep = min(CHUNK, len - t0);

    // panel = identity columns 16w..16w+15
#pragma unroll
    for (int i = 0; i < 2; ++i) *(f32x4*)(P + ((i * 64 + l) << 4)) = f32x4{0.f, 0.f, 0.f, 0.f};
    if (l < 16) *(unsigned short*)(P + padr(16 * w + l, l)) = 0x3F80;  // bf16 1.0

    const float* hb = h + ((size_t)b * TT + t0) * NN + l;
    *(unsigned short*)(ehB + wp) = f2bf(exp2f(hb[0] * LOG2E));  // same-wave in-order DS
    uint4 ua = *(uint4*)(ehB + 32 * h4);
    uint4 ub = *(uint4*)(ehB + 32 * h4 + 16);
    float hvN = hb[(size_t)min(1, nstep - 1) * NN];
    float hvN2 = hb[(size_t)min(2, nstep - 1) * NN];
    asm volatile("" ::: "memory");

    int esum = 0, ePend = 0;
    int pp = 128;
    uint4 uaN = ua, ubN = ub;

    for (int t = 0; t < nstep; ++t) {
      // --- off-chain: prep eh(t+1) (cadence-4, lag-2 — validated R6/R9) ---
      if (t + 1 < nstep) {
        const int ec = (((t + 1) & 3) == 0) ? ePend : 0;
        esum += ec;
        *(unsigned short*)(ehB + pp + wp) = f2bf(exp2f(fmaf(hvN, LOG2E, (float)(-ec))));
        uaN = *(uint4*)(ehB + pp + 32 * h4);
        ubN = *(uint4*)(ehB + pp + 32 * h4 + 16);
        hvN = hvN2;
        hvN2 = hb[(size_t)min(t + 3, nstep - 1) * NN];
      }
      // --- chain: frag reads -> MFMA (16x16x32, validated) ---
      bf16x8 fc0 = *(bf16x8*)(P + (l << 4));
      bf16x8 fc1 = *(bf16x8*)(P + 1024 + (l << 4));
      f32x4 a[4];
#pragma unroll
      for (int I = 0; I < 4; ++I) a[I] = f32x4{0.f, 0.f, 0.f, 0.f};
#pragma unroll
      for (int I = 0; I < 4; ++I) {
        a[I] = __builtin_amdgcn_mfma_f32_16x16x32_bf16(ef[I][0], fc0, a[I], 0, 0, 0);
        a[I] = __builtin_amdgcn_mfma_f32_16x16x32_bf16(ef[I][1], fc1, a[I], 0, 0, 0);
      }
      // --- epilogue: unpack bf16 eh, row-scale, prox (cadence-4), cvt, write panel ---
      const bool meas = ((t & 3) == 2);
      float prox = 0.f;
#pragma unroll
      for (int I = 0; I < 4; ++I) {
        const unsigned d0 = (I == 0) ? ua.x : (I == 1) ? ua.z : (I == 2) ? ub.x : ub.z;
        const unsigned d1 = (I == 0) ? ua.y : (I == 1) ? ua.w : (I == 2) ? ub.y : ub.w;
        f32x4 eh = {__uint_as_float(d0 << 16), __uint_as_float(d0 & 0xffff0000u),
                    __uint_as_float(d1 << 16), __uint_as_float(d1 & 0xffff0000u)};
        f32x4 v = a[I] * eh;
        if (meas) prox = fmaxf(prox, fmaxf(fmaxf(v[0], v[1]), fmaxf(v[2], v[3])));
        *(uint2*)(P + padr(16 * I + 4 * h4, cl)) = uint2{cvtpk(v[0], v[1]), cvtpk(v[2], v[3])};
      }
      if (meas) {
        prox = fmaxf(prox, __shfl_xor(prox, 16, 64));
        prox = fmaxf(prox, __shfl_xor(prox, 32, 64));
        const float px = __int_as_float(__builtin_amdgcn_readlane(__float_as_int(prox), 5));
        ePend = (__float_as_int(px) >> 23) - 127;
      }
      ua = uaN;
      ub = ubN;
      pp ^= 128;
      asm volatile("" ::: "memory");
    }

    // final exact pow2 renorm + row-major global store (validated R6/R9)
    const float scF = __int_as_float((127 - ePend) << 23);
    esum += ePend;
    unsigned short* gm = mats + (size_t)(b * NCH + c) * 4096 + l * 64 + 16 * w;
    unsigned q[8];
#pragma unroll
    for (int p = 0; p < 8; ++p) {
      float x0 = bf2f(*(unsigned short*)(P + padr(l, 2 * p))) * scF;
      float x1 = bf2f(*(unsigned short*)(P + padr(l, 2 * p + 1))) * scF;
      q[p] = cvtpk(x0, x1);
    }
    *(uint4*)gm = uint4{q[0], q[1], q[2], q[3]};
    *(uint4*)(gm + 8) = uint4{q[4], q[5], q[6], q[7]};
    if (l == 0) scalesI[(b * NCH + c) * 4 + w] = esum;
    asm volatile("" ::: "memory");
  }
}

// ---- Kernel B: per-batch vector fold with per-panel exponent reconciliation (validated R6/R9) ----
__global__ __launch_bounds__(64) void crf_fold(const float* __restrict__ mask,
                                               const float* __restrict__ trans,
                                               const unsigned short* __restrict__ mats,
                                               const int* __restrict__ scalesI,
                                               float* __restrict__ out) {
  __shared__ float pv[NN];
  const int l = threadIdx.x;
  const int b = blockIdx.x;
  const int len = wave_len(mask, b, l);
  const int nc = (len + CHUNK - 1) / CHUNK;

  float pr = (l == SOS) ? 1.f : 0.f;
  int eA = 0;
  long esumT = 0;

  for (int c = 0; c < nc; ++c) {
    const int* sI = scalesI + (b * NCH + c) * 4;
    const int e0 = sI[0], e1 = sI[1], e2 = sI[2], e3 = sI[3];
    const int S = max(max(e0, e1), max(e2, e3));
    const int g = l >> 4;
    int dl = (g == 0) ? e0 : (g == 1) ? e1 : (g == 2) ? e2 : e3;
    dl -= S;
    pv[l] = ldexpf(pr, dl - eA);
    asm volatile("" ::: "memory");
    esumT += S + eA;

    const uint4* Mr = (const uint4*)(mats + (size_t)(b * NCH + c) * 4096 + l * 64);
    uint4 U[8];
#pragma unroll
    for (int j = 0; j < 8; ++j) U[j] = Mr[j];
    float ac0 = 0.f, ac1 = 0.f, ac2 = 0.f, ac3 = 0.f;
#pragma unroll
    for (int j = 0; j < 8; ++j) {
      f32x4 pa = *(f32x4*)(pv + j * 8);
      f32x4 pb = *(f32x4*)(pv + j * 8 + 4);
      uint4 qq = U[j];
      ac0 = fmaf(__uint_as_float(qq.x << 16), pa[0], ac0);
      ac1 = fmaf(__uint_as_float(qq.x & 0xffff0000u), pa[1], ac1);
      ac2 = fmaf(__uint_as_float(qq.y << 16), pa[2], ac2);
      ac3 = fmaf(__uint_as_float(qq.y & 0xffff0000u), pa[3], ac3);
      ac0 = fmaf(__uint_as_float(qq.z << 16), pb[0], ac0);
      ac1 = fmaf(__uint_as_float(qq.z & 0xffff0000u), pb[1], ac1);
      ac2 = fmaf(__uint_as_float(qq.w << 16), pb[2], ac2);
      ac3 = fmaf(__uint_as_float(qq.w & 0xffff0000u), pb[3], ac3);
    }
    pr = (ac0 + ac1) + (ac2 + ac3);
    float mm = pr;
#pragma unroll
    for (int m = 1; m < 64; m <<= 1) mm = fmaxf(mm, __shfl_xor(mm, m, 64));
    eA = (__float_as_int(mm) >> 23) - 127;
    asm volatile("" ::: "memory");
  }

  float s = pr * __expf(trans[EOSI * NN + l]);
#pragma unroll
  for (int m = 1; m < 64; m <<= 1) s += __shfl_xor(s, m, 64);
  if (l == 0) out[b] = __logf(s) + LN2F * (float)esumT;
}

extern "C" void kernel_launch(void* const* d_in, const int* in_sizes, int n_in,
                              void* d_out, int out_size, void* d_ws, size_t ws_size,
                              hipStream_t stream) {
  const float* h = (const float*)d_in[0];
  const float* mask = (const float*)d_in[1];
  const float* trans = (const float*)d_in[2];
  float* out = (float*)d_out;

  unsigned short* mats = (unsigned short*)d_ws;  // 32 MB
  int* scalesI = (int*)((char*)d_ws + (size_t)BATCH * NCH * 4096 * 2);  // +64 KB

  hipLaunchKernelGGL(crf_chunk, dim3(BATCH * 8), dim3(256), 0, stream, h, mask, trans, mats, scalesI);
  hipLaunchKernelGGL(crf_fold, dim3(BATCH), dim3(64), 0, stream, mask, trans, mats, scalesI, out);
}

// Round 11
// 182.221 us; speedup vs baseline: 1.3049x; 1.3049x over previous
//
#include <hip/hip_runtime.h>

#define BATCH 256
#define TT 1024
#define NN 64
#define CHUNK 64
#define NCH 16
#define SOS 1
#define EOSI 2
#define LN2F 0.6931471805599453f
#define LOG2E 1.4426950408889634f

typedef short bf16x8 __attribute__((ext_vector_type(8)));
typedef float f32x4 __attribute__((ext_vector_type(4)));

__device__ __forceinline__ unsigned short f2bf(float x) {
  unsigned u = __float_as_uint(x);
  u += 0x7fffu + ((u >> 16) & 1u);
  return (unsigned short)(u >> 16);
}
__device__ __forceinline__ float bf2f(unsigned short v) { return __uint_as_float(((unsigned)v) << 16); }
__device__ __forceinline__ unsigned cvtpk(float lo, float hi) {
  unsigned r;
  asm("v_cvt_pk_bf16_f32 %0, %1, %2" : "=v"(r) : "v"(lo), "v"(hi));
  return r;
}

// Panel-local tiled address (validated R5-R10)
__device__ __forceinline__ int padr(int k, int c) {
  return ((k >> 5) << 10) + (((k >> 3) & 3) << 8) + (c << 4) + ((k & 7) << 1);
}

__device__ __forceinline__ int wave_len(const float* mask, int b, int l) {
  float ls = 0.f;
#pragma unroll
  for (int c = 0; c < 4; ++c) {
    float4 m4 = *reinterpret_cast<const float4*>(mask + (size_t)b * TT + c * 256 + l * 4);
    ls += (m4.x + m4.y) + (m4.z + m4.w);
  }
#pragma unroll
  for (int m = 1; m < 64; m <<= 1) ls += __shfl_xor(ls, m, 64);
  return (int)(ls + 0.5f);
}

// ---- Kernel A: block = (pair cp, batch b); each of 4 waves evolves panel w of chunk cp then 15-cp ----
__global__ __launch_bounds__(256, 4) void crf_chunk(const float* __restrict__ h,
                                                    const float* __restrict__ mask,
                                                    const float* __restrict__ trans,
                                                    unsigned short* __restrict__ mats,
                                                    int* __restrict__ scalesI) {
  __shared__ __align__(16) char lds[4 * 2048 + 4 * 256];  // 4 panels + 4 bf16 eh ping-pong
  const int tid = threadIdx.x;
  const int w = tid >> 6, l = tid & 63;
  const int h4 = l >> 4, cl = l & 15;
  const int cp = blockIdx.x >> 8;      // cp-major: uniform E[64]-step blocks per dispatch window
  const int b = blockIdx.x & (BATCH - 1);

  char* P = lds + w * 2048;
  char* ehB = lds + 8192 + w * 256;
  const int wp = 2 * (16 * ((l >> 2) & 3) + 4 * (l >> 4) + (l & 3));

  const int len = wave_len(mask, b, l);

  // E fragments (A operand) — computed ONCE, reused for both chunks (validated R3-R10)
  bf16x8 ef[4][2];
#pragma unroll
  for (int I = 0; I < 4; ++I)
#pragma unroll
    for (int Kc = 0; Kc < 2; ++Kc) {
      const float* p = trans + (16 * I + cl) * 64 + 32 * Kc + 8 * h4;
      bf16x8 v;
#pragma unroll
      for (int e = 0; e < 8; ++e) v[e] = (short)f2bf(__expf(p[e]));
      ef[I][Kc] = v;
    }

  for (int half = 0; half < 2; ++half) {
    const int c = half ? (NCH - 1 - cp) : cp;
    const int t0 = c * CHUNK;
    if (t0 >= len) continue;
    const int nstep = min(CHUNK, len - t0);

    // panel = identity columns 16w..16w+15
#pragma unroll
    for (int i = 0; i < 2; ++i) *(f32x4*)(P + ((i * 64 + l) << 4)) = f32x4{0.f, 0.f, 0.f, 0.f};
    if (l < 16) *(unsigned short*)(P + padr(16 * w + l, l)) = 0x3F80;  // bf16 1.0

    const float* hb = h + ((size_t)b * TT + t0) * NN + l;
    *(unsigned short*)(ehB + wp) = f2bf(exp2f(hb[0] * LOG2E));  // same-wave in-order DS
    uint4 ua = *(uint4*)(ehB + 32 * h4);
    uint4 ub = *(uint4*)(ehB + 32 * h4 + 16);
    float hvN = hb[(size_t)min(1, nstep - 1) * NN];
    float hvN2 = hb[(size_t)min(2, nstep - 1) * NN];
    asm volatile("" ::: "memory");

    int esum = 0, ePend = 0;
    int pp = 128;
    uint4 uaN = ua, ubN = ub;

    for (int t = 0; t < nstep; ++t) {
      // --- off-chain: prep eh(t+1) (cadence-4, lag-2 — validated R6/R9) ---
      if (t + 1 < nstep) {
        const int ec = (((t + 1) & 3) == 0) ? ePend : 0;
        esum += ec;
        *(unsigned short*)(ehB + pp + wp) = f2bf(exp2f(fmaf(hvN, LOG2E, (float)(-ec))));
        uaN = *(uint4*)(ehB + pp + 32 * h4);
        ubN = *(uint4*)(ehB + pp + 32 * h4 + 16);
        hvN = hvN2;
        hvN2 = hb[(size_t)min(t + 3, nstep - 1) * NN];
      }
      // --- chain: frag reads -> MFMA (16x16x32, validated) ---
      bf16x8 fc0 = *(bf16x8*)(P + (l << 4));
      bf16x8 fc1 = *(bf16x8*)(P + 1024 + (l << 4));
      f32x4 a[4];
#pragma unroll
      for (int I = 0; I < 4; ++I) a[I] = f32x4{0.f, 0.f, 0.f, 0.f};
#pragma unroll
      for (int I = 0; I < 4; ++I) {
        a[I] = __builtin_amdgcn_mfma_f32_16x16x32_bf16(ef[I][0], fc0, a[I], 0, 0, 0);
        a[I] = __builtin_amdgcn_mfma_f32_16x16x32_bf16(ef[I][1], fc1, a[I], 0, 0, 0);
      }
      // --- epilogue: unpack bf16 eh, row-scale, prox (cadence-4), cvt, write panel ---
      const bool meas = ((t & 3) == 2);
      float prox = 0.f;
#pragma unroll
      for (int I = 0; I < 4; ++I) {
        const unsigned d0 = (I == 0) ? ua.x : (I == 1) ? ua.z : (I == 2) ? ub.x : ub.z;
        const unsigned d1 = (I == 0) ? ua.y : (I == 1) ? ua.w : (I == 2) ? ub.y : ub.w;
        f32x4 eh = {__uint_as_float(d0 << 16), __uint_as_float(d0 & 0xffff0000u),
                    __uint_as_float(d1 << 16), __uint_as_float(d1 & 0xffff0000u)};
        f32x4 v = a[I] * eh;
        if (meas) prox = fmaxf(prox, fmaxf(fmaxf(v[0], v[1]), fmaxf(v[2], v[3])));
        *(uint2*)(P + padr(16 * I + 4 * h4, cl)) = uint2{cvtpk(v[0], v[1]), cvtpk(v[2], v[3])};
      }
      if (meas) {
        prox = fmaxf(prox, __shfl_xor(prox, 16, 64));
        prox = fmaxf(prox, __shfl_xor(prox, 32, 64));
        const float px = __int_as_float(__builtin_amdgcn_readlane(__float_as_int(prox), 5));
        ePend = (__float_as_int(px) >> 23) - 127;
      }
      ua = uaN;
      ub = ubN;
      pp ^= 128;
      asm volatile("" ::: "memory");
    }

    // final exact pow2 renorm + row-major global store (validated R6/R9)
    const float scF = __int_as_float((127 - ePend) << 23);
    esum += ePend;
    unsigned short* gm = mats + (size_t)(b * NCH + c) * 4096 + l * 64 + 16 * w;
    unsigned q[8];
#pragma unroll
    for (int p = 0; p < 8; ++p) {
      float x0 = bf2f(*(unsigned short*)(P + padr(l, 2 * p))) * scF;
      float x1 = bf2f(*(unsigned short*)(P + padr(l, 2 * p + 1))) * scF;
      q[p] = cvtpk(x0, x1);
    }
    *(uint4*)gm = uint4{q[0], q[1], q[2], q[3]};
    *(uint4*)(gm + 8) = uint4{q[4], q[5], q[6], q[7]};
    if (l == 0) scalesI[(b * NCH + c) * 4 + w] = esum;
    asm volatile("" ::: "memory");
  }
}

// ---- Kernel B: per-batch vector fold with per-panel exponent reconciliation (validated R6/R9) ----
__global__ __launch_bounds__(64) void crf_fold(const float* __restrict__ mask,
                                               const float* __restrict__ trans,
                                               const unsigned short* __restrict__ mats,
                                               const int* __restrict__ scalesI,
                                               float* __restrict__ out) {
  __shared__ float pv[NN];
  const int l = threadIdx.x;
  const int b = blockIdx.x;
  const int len = wave_len(mask, b, l);
  const int nc = (len + CHUNK - 1) / CHUNK;

  float pr = (l == SOS) ? 1.f : 0.f;
  int eA = 0;
  long esumT = 0;

  for (int c = 0; c < nc; ++c) {
    const int* sI = scalesI + (b * NCH + c) * 4;
    const int e0 = sI[0], e1 = sI[1], e2 = sI[2], e3 = sI[3];
    const int S = max(max(e0, e1), max(e2, e3));
    const int g = l >> 4;
    int dl = (g == 0) ? e0 : (g == 1) ? e1 : (g == 2) ? e2 : e3;
    dl -= S;
    pv[l] = ldexpf(pr, dl - eA);
    asm volatile("" ::: "memory");
    esumT += S + eA;

    const uint4* Mr = (const uint4*)(mats + (size_t)(b * NCH + c) * 4096 + l * 64);
    uint4 U[8];
#pragma unroll
    for (int j = 0; j < 8; ++j) U[j] = Mr[j];
    float ac0 = 0.f, ac1 = 0.f, ac2 = 0.f, ac3 = 0.f;
#pragma unroll
    for (int j = 0; j < 8; ++j) {
      f32x4 pa = *(f32x4*)(pv + j * 8);
      f32x4 pb = *(f32x4*)(pv + j * 8 + 4);
      uint4 qq = U[j];
      ac0 = fmaf(__uint_as_float(qq.x << 16), pa[0], ac0);
      ac1 = fmaf(__uint_as_float(qq.x & 0xffff0000u), pa[1], ac1);
      ac2 = fmaf(__uint_as_float(qq.y << 16), pa[2], ac2);
      ac3 = fmaf(__uint_as_float(qq.y & 0xffff0000u), pa[3], ac3);
      ac0 = fmaf(__uint_as_float(qq.z << 16), pb[0], ac0);
      ac1 = fmaf(__uint_as_float(qq.z & 0xffff0000u), pb[1], ac1);
      ac2 = fmaf(__uint_as_float(qq.w << 16), pb[2], ac2);
      ac3 = fmaf(__uint_as_float(qq.w & 0xffff0000u), pb[3], ac3);
    }
    pr = (ac0 + ac1) + (ac2 + ac3);
    float mm = pr;
#pragma unroll
    for (int m = 1; m < 64; m <<= 1) mm = fmaxf(mm, __shfl_xor(mm, m, 64));
    eA = (__float_as_int(mm) >> 23) - 127;
    asm volatile("" ::: "memory");
  }

  float s = pr * __expf(trans[EOSI * NN + l]);
#pragma unroll
  for (int m = 1; m < 64; m <<= 1) s += __shfl_xor(s, m, 64);
  if (l == 0) out[b] = __logf(s) + LN2F * (float)esumT;
}

extern "C" void kernel_launch(void* const* d_in, const int* in_sizes, int n_in,
                              void* d_out, int out_size, void* d_ws, size_t ws_size,
                              hipStream_t stream) {
  const float* h = (const float*)d_in[0];
  const float* mask = (const float*)d_in[1];
  const float* trans = (const float*)d_in[2];
  float* out = (float*)d_out;

  unsigned short* mats = (unsigned short*)d_ws;  // 32 MB
  int* scalesI = (int*)((char*)d_ws + (size_t)BATCH * NCH * 4096 * 2);  // +64 KB

  hipLaunchKernelGGL(crf_chunk, dim3(BATCH * 8), dim3(256), 0, stream, h, mask, trans, mats, scalesI);
  hipLaunchKernelGGL(crf_fold, dim3(BATCH), dim3(64), 0, stream, mask, trans, mats, scalesI, out);
}

// Round 12
// 171.127 us; speedup vs baseline: 1.3895x; 1.0648x over previous
//
#include <hip/hip_runtime.h>

#define BATCH 256
#define TT 1024
#define NN 64
#define CHUNK 64
#define NCH 16
#define SOS 1
#define EOSI 2
#define LN2F 0.6931471805599453f
#define LOG2E 1.4426950408889634f

typedef short bf16x8 __attribute__((ext_vector_type(8)));
typedef float f32x4 __attribute__((ext_vector_type(4)));

__device__ __forceinline__ unsigned short f2bf(float x) {
  unsigned u = __float_as_uint(x);
  u += 0x7fffu + ((u >> 16) & 1u);
  return (unsigned short)(u >> 16);
}
__device__ __forceinline__ float bf2f(unsigned short v) { return __uint_as_float(((unsigned)v) << 16); }
__device__ __forceinline__ unsigned cvtpk(float lo, float hi) {
  unsigned r;
  asm("v_cvt_pk_bf16_f32 %0, %1, %2" : "=v"(r) : "v"(lo), "v"(hi));
  return r;
}

// Full 64x64 tiled address (validated R4/R5): B-frag (J,Kc) at J*2048 + Kc*1024 + 16*lane
__device__ __forceinline__ int tadr(int k, int c) {
  return ((c >> 4) << 11) + ((k >> 5) << 10) + (((k >> 3) & 3) << 8) + ((c & 15) << 4) + ((k & 7) << 1);
}

__device__ __forceinline__ int wave_len(const float* mask, int b, int l) {
  float ls = 0.f;
#pragma unroll
  for (int c = 0; c < 4; ++c) {
    float4 m4 = *reinterpret_cast<const float4*>(mask + (size_t)b * TT + c * 256 + l * 4);
    ls += (m4.x + m4.y) + (m4.z + m4.w);
  }
#pragma unroll
  for (int m = 1; m < 64; m <<= 1) ls += __shfl_xor(ls, m, 64);
  return (int)(ls + 0.5f);
}

// ---- Kernel A: ONE wave per block; block (cp,b) runs chunk cp then 15-cp (E[steps]=64 per block) ----
__global__ __launch_bounds__(64, 4) void crf_chunk(const float* __restrict__ h,
                                                   const float* __restrict__ mask,
                                                   const float* __restrict__ trans,
                                                   unsigned short* __restrict__ mats,
                                                   int* __restrict__ scalesI) {
  __shared__ __align__(16) char lds[8192 + 256];  // 64x64 panel + bf16 eh ping-pong (2x128B)
  char* P = lds;
  char* ehB = lds + 8192;
  const int l = threadIdx.x;
  const int h4 = l >> 4, cl = l & 15;
  const int cp = blockIdx.x >> 8;
  const int b = blockIdx.x & (BATCH - 1);
  const int wp = 2 * (16 * ((l >> 2) & 3) + 4 * (l >> 4) + (l & 3));  // eh tiling (validated R9)

  const int len = wave_len(mask, b, l);

  // E fragments (A operand) — once, reused for both chunks (validated R3-R11)
  bf16x8 ef[4][2];
#pragma unroll
  for (int I = 0; I < 4; ++I)
#pragma unroll
    for (int Kc = 0; Kc < 2; ++Kc) {
      const float* p = trans + (16 * I + cl) * 64 + 32 * Kc + 8 * h4;
      bf16x8 v;
#pragma unroll
      for (int e = 0; e < 8; ++e) v[e] = (short)f2bf(__expf(p[e]));
      ef[I][Kc] = v;
    }

  for (int half = 0; half < 2; ++half) {
    const int c = half ? (NCH - 1 - cp) : cp;
    const int t0 = c * CHUNK;
    if (t0 >= len) continue;
    const int nstep = min(CHUNK, len - t0);

    // panel = 64x64 identity (tiled)
#pragma unroll
    for (int i = 0; i < 8; ++i) *(f32x4*)(P + ((i * 64 + l) << 4)) = f32x4{0.f, 0.f, 0.f, 0.f};
    *(unsigned short*)(P + tadr(l, l)) = 0x3F80;  // bf16 1.0

    const float* hb = h + ((size_t)b * TT + t0) * NN + l;
    *(unsigned short*)(ehB + wp) = f2bf(exp2f(hb[0] * LOG2E));  // same-wave in-order DS
    uint4 ua = *(uint4*)(ehB + 32 * h4);
    uint4 ub = *(uint4*)(ehB + 32 * h4 + 16);
    float hvN = hb[(size_t)min(1, nstep - 1) * NN];
    float hvN2 = hb[(size_t)min(2, nstep - 1) * NN];
    asm volatile("" ::: "memory");

    int esum = 0, ePend = 0;
    int pp = 128;
    uint4 uaN = ua, ubN = ub;

    for (int t = 0; t < nstep; ++t) {
      // --- off-chain: prep eh(t+1) (cadence-4, lag-2 — validated R9/R11) ---
      if (t + 1 < nstep) {
        const int ec = (((t + 1) & 3) == 0) ? ePend : 0;
        esum += ec;
        *(unsigned short*)(ehB + pp + wp) = f2bf(exp2f(fmaf(hvN, LOG2E, (float)(-ec))));
        uaN = *(uint4*)(ehB + pp + 32 * h4);
        ubN = *(uint4*)(ehB + pp + 32 * h4 + 16);
        hvN = hvN2;
        hvN2 = hb[(size_t)min(t + 3, nstep - 1) * NN];
      }
      // unpack eh once per step (reused across all 4 J-blocks)
      f32x4 eh4[4];
#pragma unroll
      for (int I = 0; I < 4; ++I) {
        const unsigned d0 = (I == 0) ? ua.x : (I == 1) ? ua.z : (I == 2) ? ub.x : ub.z;
        const unsigned d1 = (I == 0) ? ua.y : (I == 1) ? ua.w : (I == 2) ? ub.y : ub.w;
        eh4[I] = f32x4{__uint_as_float(d0 << 16), __uint_as_float(d0 & 0xffff0000u),
                       __uint_as_float(d1 << 16), __uint_as_float(d1 & 0xffff0000u)};
      }
      // --- chain: frag reads (dbuf) -> MFMA -> epilogue -> in-place writes (validated R5) ---
      const bool meas = ((t & 3) == 2);
      float prox = 0.f;
      bf16x8 fc0 = *(bf16x8*)(P + (l << 4));
      bf16x8 fc1 = *(bf16x8*)(P + 1024 + (l << 4));
#pragma unroll
      for (int J = 0; J < 4; ++J) {
        bf16x8 fn0, fn1;
        if (J < 3) {  // next block's frags: read before this block's writes (disjoint, in-order)
          fn0 = *(bf16x8*)(P + (2 * J + 2) * 1024 + (l << 4));
          fn1 = *(bf16x8*)(P + (2 * J + 3) * 1024 + (l << 4));
        }
        f32x4 a[4];
#pragma unroll
        for (int I = 0; I < 4; ++I) a[I] = f32x4{0.f, 0.f, 0.f, 0.f};
#pragma unroll
        for (int I = 0; I < 4; ++I) {
          a[I] = __builtin_amdgcn_mfma_f32_16x16x32_bf16(ef[I][0], fc0, a[I], 0, 0, 0);
          a[I] = __builtin_amdgcn_mfma_f32_16x16x32_bf16(ef[I][1], fc1, a[I], 0, 0, 0);
        }
#pragma unroll
        for (int I = 0; I < 4; ++I) {
          f32x4 v = a[I] * eh4[I];
          if (meas && J == 0) prox = fmaxf(prox, fmaxf(fmaxf(v[0], v[1]), fmaxf(v[2], v[3])));
          *(uint2*)(P + tadr(16 * I + 4 * h4, 16 * J + cl)) = uint2{cvtpk(v[0], v[1]), cvtpk(v[2], v[3])};
        }
        fc0 = fn0;
        fc1 = fn1;
      }
      if (meas) {  // full-column max over cols 0-15; proxy col 5 (validated R9)
        prox = fmaxf(prox, __shfl_xor(prox, 16, 64));
        prox = fmaxf(prox, __shfl_xor(prox, 32, 64));
        const float px = __int_as_float(__builtin_amdgcn_readlane(__float_as_int(prox), 5));
        ePend = (__float_as_int(px) >> 23) - 127;
      }
      ua = uaN;
      ub = ubN;
      pp ^= 128;
      asm volatile("" ::: "memory");
    }

    // final exact pow2 renorm + row-major global store (validated R4)
    const float scF = __int_as_float((127 - ePend) << 23);
    esum += ePend;
    unsigned short* gm = mats + (size_t)(b * NCH + c) * 4096;
#pragma unroll
    for (int j0 = 0; j0 < 64; j0 += 8) {
      unsigned q[4];
#pragma unroll
      for (int p = 0; p < 4; ++p) {
        float x0 = bf2f(*(unsigned short*)(P + tadr(l, j0 + 2 * p))) * scF;
        float x1 = bf2f(*(unsigned short*)(P + tadr(l, j0 + 2 * p + 1))) * scF;
        q[p] = cvtpk(x0, x1);
      }
      *(uint4*)(gm + l * 64 + j0) = uint4{q[0], q[1], q[2], q[3]};
    }
    if (l < 4) scalesI[(b * NCH + c) * 4 + l] = esum;  // uniform exponent to all 4 slots
    asm volatile("" ::: "memory");
  }
}

// ---- Kernel B: per-batch vector fold with exponent reconciliation (validated R6/R9/R11) ----
__global__ __launch_bounds__(64) void crf_fold(const float* __restrict__ mask,
                                               const float* __restrict__ trans,
                                               const unsigned short* __restrict__ mats,
                                               const int* __restrict__ scalesI,
                                               float* __restrict__ out) {
  __shared__ float pv[NN];
  const int l = threadIdx.x;
  const int b = blockIdx.x;
  const int len = wave_len(mask, b, l);
  const int nc = (len + CHUNK - 1) / CHUNK;

  float pr = (l == SOS) ? 1.f : 0.f;
  int eA = 0;
  long esumT = 0;

  for (int c = 0; c < nc; ++c) {
    const int* sI = scalesI + (b * NCH + c) * 4;
    const int e0 = sI[0], e1 = sI[1], e2 = sI[2], e3 = sI[3];
    const int S = max(max(e0, e1), max(e2, e3));
    const int g = l >> 4;
    int dl = (g == 0) ? e0 : (g == 1) ? e1 : (g == 2) ? e2 : e3;
    dl -= S;
    pv[l] = ldexpf(pr, dl - eA);
    asm volatile("" ::: "memory");
    esumT += S + eA;

    const uint4* Mr = (const uint4*)(mats + (size_t)(b * NCH + c) * 4096 + l * 64);
    uint4 U[8];
#pragma unroll
    for (int j = 0; j < 8; ++j) U[j] = Mr[j];
    float ac0 = 0.f, ac1 = 0.f, ac2 = 0.f, ac3 = 0.f;
#pragma unroll
    for (int j = 0; j < 8; ++j) {
      f32x4 pa = *(f32x4*)(pv + j * 8);
      f32x4 pb = *(f32x4*)(pv + j * 8 + 4);
      uint4 qq = U[j];
      ac0 = fmaf(__uint_as_float(qq.x << 16), pa[0], ac0);
      ac1 = fmaf(__uint_as_float(qq.x & 0xffff0000u), pa[1], ac1);
      ac2 = fmaf(__uint_as_float(qq.y << 16), pa[2], ac2);
      ac3 = fmaf(__uint_as_float(qq.y & 0xffff0000u), pa[3], ac3);
      ac0 = fmaf(__uint_as_float(qq.z << 16), pb[0], ac0);
      ac1 = fmaf(__uint_as_float(qq.z & 0xffff0000u), pb[1], ac1);
      ac2 = fmaf(__uint_as_float(qq.w << 16), pb[2], ac2);
      ac3 = fmaf(__uint_as_float(qq.w & 0xffff0000u), pb[3], ac3);
    }
    pr = (ac0 + ac1) + (ac2 + ac3);
    float mm = pr;
#pragma unroll
    for (int m = 1; m < 64; m <<= 1) mm = fmaxf(mm, __shfl_xor(mm, m, 64));
    eA = (__float_as_int(mm) >> 23) - 127;
    asm volatile("" ::: "memory");
  }

  float s = pr * __expf(trans[EOSI * NN + l]);
#pragma unroll
  for (int m = 1; m < 64; m <<= 1) s += __shfl_xor(s, m, 64);
  if (l == 0) out[b] = __logf(s) + LN2F * (float)esumT;
}

extern "C" void kernel_launch(void* const* d_in, const int* in_sizes, int n_in,
                              void* d_out, int out_size, void* d_ws, size_t ws_size,
                              hipStream_t stream) {
  const float* h = (const float*)d_in[0];
  const float* mask = (const float*)d_in[1];
  const float* trans = (const float*)d_in[2];
  float* out = (float*)d_out;

  unsigned short* mats = (unsigned short*)d_ws;  // 32 MB
  int* scalesI = (int*)((char*)d_ws + (size_t)BATCH * NCH * 4096 * 2);  // +64 KB

  hipLaunchKernelGGL(crf_chunk, dim3(8 * BATCH), dim3(64), 0, stream, h, mask, trans, mats, scalesI);
  hipLaunchKernelGGL(crf_fold, dim3(BATCH), dim3(64), 0, stream, mask, trans, mats, scalesI, out);
}

// Round 13
// 170.930 us; speedup vs baseline: 1.3911x; 1.0012x over previous
//
#include <hip/hip_runtime.h>

#define BATCH 256
#define TT 1024
#define NN 64
#define CHUNK 64
#define NCH 16
#define SOS 1
#define EOSI 2
#define LN2F 0.6931471805599453f
#define LOG2E 1.4426950408889634f

typedef short bf16x8 __attribute__((ext_vector_type(8)));
typedef float f32x4 __attribute__((ext_vector_type(4)));

__device__ __forceinline__ unsigned short f2bf(float x) {
  unsigned u = __float_as_uint(x);
  u += 0x7fffu + ((u >> 16) & 1u);
  return (unsigned short)(u >> 16);
}
__device__ __forceinline__ float bf2f(unsigned short v) { return __uint_as_float(((unsigned)v) << 16); }
__device__ __forceinline__ unsigned cvtpk(float lo, float hi) {
  unsigned r;
  asm("v_cvt_pk_bf16_f32 %0, %1, %2" : "=v"(r) : "v"(lo), "v"(hi));
  return r;
}

// Full 64x64 tiled address (validated R4/R5/R12): B-frag (J,Kc) at J*2048 + Kc*1024 + 16*lane
__device__ __forceinline__ int tadr(int k, int c) {
  return ((c >> 4) << 11) + ((k >> 5) << 10) + (((k >> 3) & 3) << 8) + ((c & 15) << 4) + ((k & 7) << 1);
}

__device__ __forceinline__ int wave_len(const float* mask, int b, int l) {
  float ls = 0.f;
#pragma unroll
  for (int c = 0; c < 4; ++c) {
    float4 m4 = *reinterpret_cast<const float4*>(mask + (size_t)b * TT + c * 256 + l * 4);
    ls += (m4.x + m4.y) + (m4.z + m4.w);
  }
#pragma unroll
  for (int m = 1; m < 64; m <<= 1) ls += __shfl_xor(ls, m, 64);
  return (int)(ls + 0.5f);
}

// ---- Kernel A: ONE wave per block; block (b,cp) runs chunk cp then 15-cp (E[steps]=64) ----
// Grid encoding: cp in LOW bits so round-robin dispatch spreads each batch's pairs
// across CUs (CU k gets 8 DIFFERENT batches) — the R10-validated balance property.
__global__ __launch_bounds__(64, 4) void crf_chunk(const float* __restrict__ h,
                                                   const float* __restrict__ mask,
                                                   const float* __restrict__ trans,
                                                   unsigned short* __restrict__ mats,
                                                   int* __restrict__ scalesI) {
  __shared__ __align__(16) char lds[8192 + 256];  // 64x64 panel + bf16 eh ping-pong (2x128B)
  char* P = lds;
  char* ehB = lds + 8192;
  const int l = threadIdx.x;
  const int h4 = l >> 4, cl = l & 15;
  const int cp = blockIdx.x & 7;   // pair index in LOW bits (balance)
  const int b = blockIdx.x >> 3;   // batch in HIGH bits
  const int wp = 2 * (16 * ((l >> 2) & 3) + 4 * (l >> 4) + (l & 3));  // eh tiling (validated R9)

  const int len = wave_len(mask, b, l);

  // E fragments (A operand) — once, reused for both chunks (validated R3-R12)
  bf16x8 ef[4][2];
#pragma unroll
  for (int I = 0; I < 4; ++I)
#pragma unroll
    for (int Kc = 0; Kc < 2; ++Kc) {
      const float* p = trans + (16 * I + cl) * 64 + 32 * Kc + 8 * h4;
      bf16x8 v;
#pragma unroll
      for (int e = 0; e < 8; ++e) v[e] = (short)f2bf(__expf(p[e]));
      ef[I][Kc] = v;
    }

  for (int half = 0; half < 2; ++half) {
    const int c = half ? (NCH - 1 - cp) : cp;
    const int t0 = c * CHUNK;
    if (t0 >= len) continue;
    const int nstep = min(CHUNK, len - t0);

    // panel = 64x64 identity (tiled)
#pragma unroll
    for (int i = 0; i < 8; ++i) *(f32x4*)(P + ((i * 64 + l) << 4)) = f32x4{0.f, 0.f, 0.f, 0.f};
    *(unsigned short*)(P + tadr(l, l)) = 0x3F80;  // bf16 1.0

    const float* hb = h + ((size_t)b * TT + t0) * NN + l;
    *(unsigned short*)(ehB + wp) = f2bf(exp2f(hb[0] * LOG2E));  // same-wave in-order DS
    uint4 ua = *(uint4*)(ehB + 32 * h4);
    uint4 ub = *(uint4*)(ehB + 32 * h4 + 16);
    float hvN = hb[(size_t)min(1, nstep - 1) * NN];
    float hvN2 = hb[(size_t)min(2, nstep - 1) * NN];
    asm volatile("" ::: "memory");

    int esum = 0, ePend = 0;
    int pp = 128;
    uint4 uaN = ua, ubN = ub;

    for (int t = 0; t < nstep; ++t) {
      // --- off-chain: prep eh(t+1) (cadence-4, lag-2 — validated R9/R11/R12) ---
      if (t + 1 < nstep) {
        const int ec = (((t + 1) & 3) == 0) ? ePend : 0;
        esum += ec;
        *(unsigned short*)(ehB + pp + wp) = f2bf(exp2f(fmaf(hvN, LOG2E, (float)(-ec))));
        uaN = *(uint4*)(ehB + pp + 32 * h4);
        ubN = *(uint4*)(ehB + pp + 32 * h4 + 16);
        hvN = hvN2;
        hvN2 = hb[(size_t)min(t + 3, nstep - 1) * NN];
      }
      // unpack eh once per step (reused across all 4 J-blocks)
      f32x4 eh4[4];
#pragma unroll
      for (int I = 0; I < 4; ++I) {
        const unsigned d0 = (I == 0) ? ua.x : (I == 1) ? ua.z : (I == 2) ? ub.x : ub.z;
        const unsigned d1 = (I == 0) ? ua.y : (I == 1) ? ua.w : (I == 2) ? ub.y : ub.w;
        eh4[I] = f32x4{__uint_as_float(d0 << 16), __uint_as_float(d0 & 0xffff0000u),
                       __uint_as_float(d1 << 16), __uint_as_float(d1 & 0xffff0000u)};
      }
      // --- chain: frag reads (dbuf) -> MFMA -> epilogue -> in-place writes (validated R5/R12) ---
      const bool meas = ((t & 3) == 2);
      float prox = 0.f;
      bf16x8 fc0 = *(bf16x8*)(P + (l << 4));
      bf16x8 fc1 = *(bf16x8*)(P + 1024 + (l << 4));
#pragma unroll
      for (int J = 0; J < 4; ++J) {
        bf16x8 fn0, fn1;
        if (J < 3) {  // next block's frags: read before this block's writes (disjoint, in-order)
          fn0 = *(bf16x8*)(P + (2 * J + 2) * 1024 + (l << 4));
          fn1 = *(bf16x8*)(P + (2 * J + 3) * 1024 + (l << 4));
        }
        f32x4 a[4];
#pragma unroll
        for (int I = 0; I < 4; ++I) a[I] = f32x4{0.f, 0.f, 0.f, 0.f};
#pragma unroll
        for (int I = 0; I < 4; ++I) {
          a[I] = __builtin_amdgcn_mfma_f32_16x16x32_bf16(ef[I][0], fc0, a[I], 0, 0, 0);
          a[I] = __builtin_amdgcn_mfma_f32_16x16x32_bf16(ef[I][1], fc1, a[I], 0, 0, 0);
        }
#pragma unroll
        for (int I = 0; I < 4; ++I) {
          f32x4 v = a[I] * eh4[I];
          if (meas && J == 0) prox = fmaxf(prox, fmaxf(fmaxf(v[0], v[1]), fmaxf(v[2], v[3])));
          *(uint2*)(P + tadr(16 * I + 4 * h4, 16 * J + cl)) = uint2{cvtpk(v[0], v[1]), cvtpk(v[2], v[3])};
        }
        fc0 = fn0;
        fc1 = fn1;
      }
      if (meas) {  // full-column max over cols 0-15; proxy col 5 (validated R9/R12)
        prox = fmaxf(prox, __shfl_xor(prox, 16, 64));
        prox = fmaxf(prox, __shfl_xor(prox, 32, 64));
        const float px = __int_as_float(__builtin_amdgcn_readlane(__float_as_int(prox), 5));
        ePend = (__float_as_int(px) >> 23) - 127;
      }
      ua = uaN;
      ub = ubN;
      pp ^= 128;
      asm volatile("" ::: "memory");
    }

    // final exact pow2 renorm + row-major global store (validated R4/R12)
    const float scF = __int_as_float((127 - ePend) << 23);
    esum += ePend;
    unsigned short* gm = mats + (size_t)(b * NCH + c) * 4096;
#pragma unroll
    for (int j0 = 0; j0 < 64; j0 += 8) {
      unsigned q[4];
#pragma unroll
      for (int p = 0; p < 4; ++p) {
        float x0 = bf2f(*(unsigned short*)(P + tadr(l, j0 + 2 * p))) * scF;
        float x1 = bf2f(*(unsigned short*)(P + tadr(l, j0 + 2 * p + 1))) * scF;
        q[p] = cvtpk(x0, x1);
      }
      *(uint4*)(gm + l * 64 + j0) = uint4{q[0], q[1], q[2], q[3]};
    }
    if (l < 4) scalesI[(b * NCH + c) * 4 + l] = esum;  // uniform exponent to all 4 slots
    asm volatile("" ::: "memory");
  }
}

// ---- Kernel B: per-batch vector fold with exponent reconciliation (validated R6/R9/R11/R12) ----
__global__ __launch_bounds__(64) void crf_fold(const float* __restrict__ mask,
                                               const float* __restrict__ trans,
                                               const unsigned short* __restrict__ mats,
                                               const int* __restrict__ scalesI,
                                               float* __restrict__ out) {
  __shared__ float pv[NN];
  const int l = threadIdx.x;
  const int b = blockIdx.x;
  const int len = wave_len(mask, b, l);
  const int nc = (len + CHUNK - 1) / CHUNK;

  float pr = (l == SOS) ? 1.f : 0.f;
  int eA = 0;
  long esumT = 0;

  for (int c = 0; c < nc; ++c) {
    const int* sI = scalesI + (b * NCH + c) * 4;
    const int e0 = sI[0], e1 = sI[1], e2 = sI[2], e3 = sI[3];
    const int S = max(max(e0, e1), max(e2, e3));
    const int g = l >> 4;
    int dl = (g == 0) ? e0 : (g == 1) ? e1 : (g == 2) ? e2 : e3;
    dl -= S;
    pv[l] = ldexpf(pr, dl - eA);
    asm volatile("" ::: "memory");
    esumT += S + eA;

    const uint4* Mr = (const uint4*)(mats + (size_t)(b * NCH + c) * 4096 + l * 64);
    uint4 U[8];
#pragma unroll
    for (int j = 0; j < 8; ++j) U[j] = Mr[j];
    float ac0 = 0.f, ac1 = 0.f, ac2 = 0.f, ac3 = 0.f;
#pragma unroll
    for (int j = 0; j < 8; ++j) {
      f32x4 pa = *(f32x4*)(pv + j * 8);
      f32x4 pb = *(f32x4*)(pv + j * 8 + 4);
      uint4 qq = U[j];
      ac0 = fmaf(__uint_as_float(qq.x << 16), pa[0], ac0);
      ac1 = fmaf(__uint_as_float(qq.x & 0xffff0000u), pa[1], ac1);
      ac2 = fmaf(__uint_as_float(qq.y << 16), pa[2], ac2);
      ac3 = fmaf(__uint_as_float(qq.y & 0xffff0000u), pa[3], ac3);
      ac0 = fmaf(__uint_as_float(qq.z << 16), pb[0], ac0);
      ac1 = fmaf(__uint_as_float(qq.z & 0xffff0000u), pb[1], ac1);
      ac2 = fmaf(__uint_as_float(qq.w << 16), pb[2], ac2);
      ac3 = fmaf(__uint_as_float(qq.w & 0xffff0000u), pb[3], ac3);
    }
    pr = (ac0 + ac1) + (ac2 + ac3);
    float mm = pr;
#pragma unroll
    for (int m = 1; m < 64; m <<= 1) mm = fmaxf(mm, __shfl_xor(mm, m, 64));
    eA = (__float_as_int(mm) >> 23) - 127;
    asm volatile("" ::: "memory");
  }

  float s = pr * __expf(trans[EOSI * NN + l]);
#pragma unroll
  for (int m = 1; m < 64; m <<= 1) s += __shfl_xor(s, m, 64);
  if (l == 0) out[b] = __logf(s) + LN2F * (float)esumT;
}

extern "C" void kernel_launch(void* const* d_in, const int* in_sizes, int n_in,
                              void* d_out, int out_size, void* d_ws, size_t ws_size,
                              hipStream_t stream) {
  const float* h = (const float*)d_in[0];
  const float* mask = (const float*)d_in[1];
  const float* trans = (const float*)d_in[2];
  float* out = (float*)d_out;

  unsigned short* mats = (unsigned short*)d_ws;  // 32 MB
  int* scalesI = (int*)((char*)d_ws + (size_t)BATCH * NCH * 4096 * 2);  // +64 KB

  hipLaunchKernelGGL(crf_chunk, dim3(BATCH * 8), dim3(64), 0, stream, h, mask, trans, mats, scalesI);
  hipLaunchKernelGGL(crf_fold, dim3(BATCH), dim3(64), 0, stream, mask, trans, mats, scalesI, out);
}